// Round 12
// baseline (224.374 us; speedup 1.0000x reference)
//
#include <hip/hip_runtime.h>

// Problem constants (fixed by the reference)
constexpr int B_  = 4;
constexpr int S_  = 512;
constexpr int D_  = 256;
constexpr int HW_ = 4096;   // 64*64 spatial
constexpr int NH_ = 8;
constexpr int HD_ = 32;     // head dim
constexpr int NSPLIT = 8;   // KV splits (barrier-free loop -> TLP pays now)
constexpr int ROWS_  = B_ * NH_ * S_;      // 16384
constexpr int KVB    = 64;                 // keys per tile
constexpr int TILES  = HW_ / NSPLIT / KVB; // 8

typedef float  f32x4   __attribute__((ext_vector_type(4)));
typedef float  f32x16  __attribute__((ext_vector_type(16)));
typedef short  s16x4   __attribute__((ext_vector_type(4)));
typedef short  s16x8   __attribute__((ext_vector_type(8)));
typedef __bf16 bf16x8  __attribute__((ext_vector_type(8)));
typedef unsigned int u32x2 __attribute__((ext_vector_type(2)));
typedef unsigned int u32x4 __attribute__((ext_vector_type(4)));

__device__ __forceinline__ f32x4 mfma_bf16(s16x8 a, s16x8 b, f32x4 c) {
  return __builtin_amdgcn_mfma_f32_16x16x32_bf16(
      __builtin_bit_cast(bf16x8, a), __builtin_bit_cast(bf16x8, b), c, 0, 0, 0);
}
__device__ __forceinline__ f32x16 mfma32(s16x8 a, s16x8 b, f32x16 c) {
  return __builtin_amdgcn_mfma_f32_32x32x16_bf16(
      __builtin_bit_cast(bf16x8, a), __builtin_bit_cast(bf16x8, b), c, 0, 0, 0);
}

// split fp32 -> bf16 hi (truncate) + bf16 lo (rounded residual)
__device__ __forceinline__ void split4(float4 v, s16x4& h, s16x4& l) {
  float x[4] = {v.x, v.y, v.z, v.w};
  #pragma unroll
  for (int j = 0; j < 4; ++j) {
    unsigned xb = __float_as_uint(x[j]);
    h[j] = (short)(xb >> 16);
    float lo = x[j] - __uint_as_float(xb & 0xFFFF0000u);
    l[j] = (short)((__float_as_uint(lo) + 0x8000u) >> 16);
  }
}

// pack two f32 into one u32 of 2 bf16 (truncated); lo = truncated residual
__device__ __forceinline__ unsigned pk_hi(float x, float y) {
  return (__float_as_uint(x) >> 16) | (__float_as_uint(y) & 0xFFFF0000u);
}
__device__ __forceinline__ unsigned pk_lo(float x, float y) {
  float rx = x - __uint_as_float(__float_as_uint(x) & 0xFFFF0000u);
  float ry = y - __uint_as_float(__float_as_uint(y) & 0xFFFF0000u);
  return (__float_as_uint(rx) >> 16) | (__float_as_uint(ry) & 0xFFFF0000u);
}

// ---------------------------------------------------------------------------
// prep: fused (a) KV transpose+split  (b) Q projection  (c) Wk/Wv pre-split.
// Grid 1280: [0,1024) transpose, [1024,1152) Q-proj, [1152,1280) split_w.
// ---------------------------------------------------------------------------
__global__ __launch_bounds__(256)
void prep(const float* __restrict__ KV,
          short* __restrict__ Th, short* __restrict__ Tl,
          const float* __restrict__ Wk, const float* __restrict__ Wv,
          short* __restrict__ WkH, short* __restrict__ WkL,
          short* __restrict__ WvH, short* __restrict__ WvL,
          const float* __restrict__ query, const float* __restrict__ Wq,
          const float* __restrict__ bq,
          short* __restrict__ Qh, short* __restrict__ Ql, float qalpha)
{
  union SmP {
    struct {
      short Ah[64][40], Al[64][40];
      short W0h[64][40], W0l[64][40];
    } s;
    float ep[64][76];
    float tile[64][65];
  };
  __shared__ __align__(16) SmP sm;
  const int tid = threadIdx.x;
  const int bid0 = blockIdx.x;

  if (bid0 < 1024) {
    const int hwb = bid0 & 63;
    const int db  = (bid0 >> 6) & 3;
    const int b   = bid0 >> 8;
    const int hw0 = hwb * 64, d0 = db * 64;
    #pragma unroll
    for (int i = 0; i < 4; ++i) {
      const int idx = tid + (i << 8);
      const int d = idx >> 4, h4 = idx & 15;
      *(float4*)&sm.tile[d][h4 * 4] =
          *(const float4*)&KV[((size_t)(b * D_ + d0 + d)) * HW_ + hw0 + h4 * 4];
    }
    __syncthreads();
    #pragma unroll
    for (int i = 0; i < 4; ++i) {
      const int idx = tid + (i << 8);
      const int hw = idx >> 4, d4 = idx & 15;
      const float4 v = make_float4(sm.tile[d4*4+0][hw], sm.tile[d4*4+1][hw],
                                   sm.tile[d4*4+2][hw], sm.tile[d4*4+3][hw]);
      s16x4 hh, ll; split4(v, hh, ll);
      const size_t o = ((size_t)(b * HW_ + hw0 + hw)) * D_ + d0 + d4 * 4;
      *(s16x4*)&Th[o] = hh; *(s16x4*)&Tl[o] = ll;
    }
  } else if (bid0 < 1152) {
    const int wv = tid >> 6, lane = tid & 63, lq = lane & 15, lg = lane >> 4;
    const int wm = wv >> 1, wn = wv & 1;
    int bid = bid0 - 1024;
    bid = (bid & 7) * 16 + (bid >> 3);
    const int m0 = (bid & 31) << 6, n0 = (bid >> 5) << 6;

    f32x4 acc0[2][2] = {};
    float4 aF[2], w0R[2];
    auto gload = [&](int kt) {
      const int k0 = kt << 5;
      #pragma unroll
      for (int i = 0; i < 2; ++i) {
        const int idx = tid + (i << 8);
        const int m = idx >> 3, c4 = idx & 7;
        aF[i]  = *(const float4*)&query[(size_t)(m0 + m) * D_ + k0 + c4 * 4];
        w0R[i] = *(const float4*)&Wq[(size_t)(n0 + m) * D_ + k0 + c4 * 4];
      }
    };
    auto stage = [&]() {
      #pragma unroll
      for (int i = 0; i < 2; ++i) {
        const int idx = tid + (i << 8);
        const int m = idx >> 3, c4 = idx & 7;
        s16x4 hh, ll; split4(aF[i], hh, ll);
        *(s16x4*)&sm.s.Ah[m][c4 * 4] = hh;
        *(s16x4*)&sm.s.Al[m][c4 * 4] = ll;
        float4 w = w0R[i];
        w.x *= qalpha; w.y *= qalpha; w.z *= qalpha; w.w *= qalpha;
        split4(w, hh, ll);
        *(s16x4*)&sm.s.W0h[m][c4 * 4] = hh;
        *(s16x4*)&sm.s.W0l[m][c4 * 4] = ll;
      }
    };
    gload(0);
    #pragma unroll
    for (int kt = 0; kt < 8; ++kt) {
      __syncthreads();
      stage();
      __syncthreads();
      if (kt < 7) gload(kt + 1);
      s16x8 ah[2], al[2];
      #pragma unroll
      for (int mi = 0; mi < 2; ++mi) {
        ah[mi] = *(const s16x8*)&sm.s.Ah[wm * 32 + mi * 16 + lq][lg * 8];
        al[mi] = *(const s16x8*)&sm.s.Al[wm * 32 + mi * 16 + lq][lg * 8];
      }
      #pragma unroll
      for (int ni = 0; ni < 2; ++ni) {
        const int nr = wn * 32 + ni * 16 + lq;
        const s16x8 bh = *(const s16x8*)&sm.s.W0h[nr][lg * 8];
        const s16x8 bl = *(const s16x8*)&sm.s.W0l[nr][lg * 8];
        #pragma unroll
        for (int mi = 0; mi < 2; ++mi) {
          acc0[mi][ni] = mfma_bf16(ah[mi], bh, acc0[mi][ni]);
          acc0[mi][ni] = mfma_bf16(al[mi], bh, acc0[mi][ni]);
          acc0[mi][ni] = mfma_bf16(ah[mi], bl, acc0[mi][ni]);
        }
      }
    }
    __syncthreads();
    #pragma unroll
    for (int mi = 0; mi < 2; ++mi)
      #pragma unroll
      for (int ni = 0; ni < 2; ++ni)
        #pragma unroll
        for (int r = 0; r < 4; ++r)
          sm.ep[wm*32 + mi*16 + lg*4 + r][wn*32 + ni*16 + lq] = acc0[mi][ni][r];
    __syncthreads();
    #pragma unroll
    for (int i = 0; i < 4; ++i) {
      const int idx = tid + (i << 8);
      const int m = idx >> 4, c4 = idx & 15;
      const float4 v = *(const float4*)&sm.ep[m][c4 * 4];
      const float4 bb = *(const float4*)&bq[n0 + c4 * 4];
      const float4 o = make_float4(v.x + qalpha * bb.x, v.y + qalpha * bb.y,
                                   v.z + qalpha * bb.z, v.w + qalpha * bb.w);
      s16x4 hh, ll; split4(o, hh, ll);
      const size_t off = (size_t)(m0 + m) * D_ + n0 + c4 * 4;
      *(s16x4*)&Qh[off] = hh;
      *(s16x4*)&Ql[off] = ll;
    }
  } else {
    const int idx = (bid0 - 1152) * 256 + tid;
    const int m = idx >> 14;
    const int o4 = idx & 16383;
    const float4 v = *(const float4*)&(m ? Wv : Wk)[o4 * 4];
    s16x4 hh, ll; split4(v, hh, ll);
    *(s16x4*)&(m ? WvH : WkH)[o4 * 4] = hh;
    *(s16x4*)&(m ? WvL : WkL)[o4 * 4] = ll;
  }
}

// ---------------------------------------------------------------------------
// Dual K/V projection GEMM (bf16x3) — BARRIER-FREE main loop: all fragments
// (pre-split A and W) loaded per-wave directly from global (L1/L2-served;
// W is 0.5MB L1-resident, A <=8x redundancy absorbed by L2). LDS only in
// the epilogues. K -> row-major pair; V -> transposed [b][n][hw] pair.
// ---------------------------------------------------------------------------
__global__ __launch_bounds__(256)
void gemm_kv(const short* __restrict__ Ah_, const short* __restrict__ Al_,
             const short* __restrict__ W0h_, const short* __restrict__ W0l_,
             const float* __restrict__ b0,
             short* __restrict__ C0h, short* __restrict__ C0l,
             const short* __restrict__ W1h_, const short* __restrict__ W1l_,
             const float* __restrict__ b1,
             short* __restrict__ C1h, short* __restrict__ C1l)
{
  __shared__ __align__(16) float ep[64][76];

  const int tid = threadIdx.x;
  const int wv = tid >> 6, lane = tid & 63, lq = lane & 15, lg = lane >> 4;
  const int wm = wv >> 1, wn = wv & 1;
  constexpr int nx = (B_ * HW_) >> 6;            // 256
  int bid = blockIdx.x;
  bid = (bid & 7) * 128 + (bid >> 3);            // XCD swizzle (1024 = 8*128)
  const int m0 = (bid % nx) << 6, n0 = (bid / nx) << 6;

  f32x4 acc0[2][2] = {};
  f32x4 acc1[2][2] = {};

  const size_t arow[2] = {(size_t)(m0 + wm * 32 + lq) * D_,
                          (size_t)(m0 + wm * 32 + 16 + lq) * D_};
  const size_t wrow[2] = {(size_t)(n0 + wn * 32 + lq) * D_,
                          (size_t)(n0 + wn * 32 + 16 + lq) * D_};

  #pragma unroll
  for (int kt = 0; kt < 8; ++kt) {
    const int k0 = kt * 32 + lg * 8;
    s16x8 ah[2], al[2];
    #pragma unroll
    for (int mi = 0; mi < 2; ++mi) {
      ah[mi] = *(const s16x8*)&Ah_[arow[mi] + k0];
      al[mi] = *(const s16x8*)&Al_[arow[mi] + k0];
    }
    #pragma unroll
    for (int ni = 0; ni < 2; ++ni) {
      const s16x8 bh = *(const s16x8*)&W0h_[wrow[ni] + k0];
      const s16x8 bl = *(const s16x8*)&W0l_[wrow[ni] + k0];
      #pragma unroll
      for (int mi = 0; mi < 2; ++mi) {
        acc0[mi][ni] = mfma_bf16(ah[mi], bh, acc0[mi][ni]);
        acc0[mi][ni] = mfma_bf16(al[mi], bh, acc0[mi][ni]);
        acc0[mi][ni] = mfma_bf16(ah[mi], bl, acc0[mi][ni]);
      }
      const s16x8 ch = *(const s16x8*)&W1h_[wrow[ni] + k0];
      const s16x8 cl = *(const s16x8*)&W1l_[wrow[ni] + k0];
      #pragma unroll
      for (int mi = 0; mi < 2; ++mi) {
        acc1[mi][ni] = mfma_bf16(ah[mi], ch, acc1[mi][ni]);
        acc1[mi][ni] = mfma_bf16(al[mi], ch, acc1[mi][ni]);
        acc1[mi][ni] = mfma_bf16(ah[mi], cl, acc1[mi][ni]);
      }
    }
  }

  // ---- epilogue C0 (K, row-major pair) ----
  #pragma unroll
  for (int mi = 0; mi < 2; ++mi)
    #pragma unroll
    for (int ni = 0; ni < 2; ++ni)
      #pragma unroll
      for (int r = 0; r < 4; ++r)
        ep[wm*32 + mi*16 + lg*4 + r][wn*32 + ni*16 + lq] = acc0[mi][ni][r];
  __syncthreads();
  #pragma unroll
  for (int i = 0; i < 4; ++i) {
    const int idx = tid + (i << 8);
    const int m = idx >> 4, c4 = idx & 15;
    const float4 v = *(const float4*)&ep[m][c4 * 4];
    const float4 bb = *(const float4*)&b0[n0 + c4 * 4];
    const float4 o = make_float4(v.x + bb.x, v.y + bb.y, v.z + bb.z, v.w + bb.w);
    const size_t off = (size_t)(m0 + m) * D_ + n0 + c4 * 4;
    s16x4 hh, ll; split4(o, hh, ll);
    *(s16x4*)&C0h[off] = hh;
    *(s16x4*)&C0l[off] = ll;
  }

  // ---- epilogue C1 (V, transposed [b][n][hw] pair) ----
  __syncthreads();
  #pragma unroll
  for (int mi = 0; mi < 2; ++mi)
    #pragma unroll
    for (int ni = 0; ni < 2; ++ni)
      *(f32x4*)&ep[wn*32 + ni*16 + lq][wm*32 + mi*16 + lg*4] = acc1[mi][ni];
  __syncthreads();
  const int b = m0 >> 12, hw0 = m0 & (HW_ - 1);
  #pragma unroll
  for (int i = 0; i < 4; ++i) {
    const int idx = tid + (i << 8);
    const int n = idx >> 4, m4 = idx & 15;
    const float4 v = *(const float4*)&ep[n][m4 * 4];
    const float bb = b1[n0 + n];
    const float4 o = make_float4(v.x + bb, v.y + bb, v.z + bb, v.w + bb);
    s16x4 hh, ll; split4(o, hh, ll);
    const size_t off = ((size_t)(b * D_ + n0 + n)) * HW_ + hw0 + m4 * 4;
    *(s16x4*)&C1h[off] = hh;
    *(s16x4*)&C1l[off] = ll;
  }
}

// ---------------------------------------------------------------------------
// MFMA flash attention, 32x32x16 (bf16x3), exp2 domain, static-max softmax,
// BARRIER-FREE: K and V fragments both load per-wave directly from global
// (per-tile footprints K ~4KB / V ~8KB -> L1-resident; all 4 waves share).
// No LDS, no __syncthreads in the main loop -> waves fully independent.
// ---------------------------------------------------------------------------
__global__ __launch_bounds__(256, 3)
void attn_mfma32(const short* __restrict__ Qh_, const short* __restrict__ Ql_,
                 const short* __restrict__ Kh_, const short* __restrict__ Kl_,
                 const short* __restrict__ Vth, const short* __restrict__ Vtl,
                 float* __restrict__ Opart, float* __restrict__ Ml)
{
  __shared__ __align__(16) float ep[4][32][33];   // epilogue transpose only

  const int tid  = threadIdx.x;
  const int wv   = tid >> 6, lane = tid & 63;
  const int lq   = lane & 31, hi = lane >> 5;

  int w = blockIdx.x;
  w = (w & 7) * 128 + (w >> 3);    // XCD swizzle: 1024 = 8*128, bijective
  const int qt = w & 3;            // 4 q-tiles of 128
  const int h  = (w >> 2) & 7;
  const int b  = (w >> 5) & 3;
  const int sp = w >> 7;           // in [0, NSPLIT=8)
  const int q0 = qt * 128 + wv * 32;

  // Q frags (B operand): col q = lq, k(d) = ks*16 + 8*hi + i
  s16x8 qh[2], ql[2];
  {
    const size_t qb = ((size_t)(b * S_ + q0 + lq)) * D_ + h * HD_ + hi * 8;
    qh[0] = *(const s16x8*)&Qh_[qb];      qh[1] = *(const s16x8*)&Qh_[qb + 16];
    ql[0] = *(const s16x8*)&Ql_[qb];      ql[1] = *(const s16x8*)&Ql_[qb + 16];
  }

  f32x16 o = {0.f,0.f,0.f,0.f, 0.f,0.f,0.f,0.f, 0.f,0.f,0.f,0.f, 0.f,0.f,0.f,0.f};
  float lrun = 0.f;

  const size_t vrow = ((size_t)(b * D_ + h * HD_ + lq)) * HW_;

  for (int tt = 0; tt < TILES; ++tt) {
    const int t = sp * TILES + tt;
    #pragma unroll
    for (int cc = 0; cc < 2; ++cc) {
      // ---- QK^T (swapped): S^T[key][q] for 32 keys, bf16x3 ----
      const size_t kb = ((size_t)(b * HW_ + t * KVB + cc * 32 + lq)) * D_ + h * HD_ + hi * 8;
      const s16x8 kh0 = *(const s16x8*)&Kh_[kb];
      const s16x8 kh1 = *(const s16x8*)&Kh_[kb + 16];
      const s16x8 kl0 = *(const s16x8*)&Kl_[kb];
      const s16x8 kl1 = *(const s16x8*)&Kl_[kb + 16];
      f32x16 a = {0.f,0.f,0.f,0.f, 0.f,0.f,0.f,0.f, 0.f,0.f,0.f,0.f, 0.f,0.f,0.f,0.f};
      __builtin_amdgcn_s_setprio(1);
      a = mfma32(kh0, qh[0], a);
      a = mfma32(kh1, qh[1], a);
      a = mfma32(kl0, qh[0], a);
      a = mfma32(kl1, qh[1], a);
      a = mfma32(kh0, ql[0], a);
      a = mfma32(kh1, ql[1], a);
      __builtin_amdgcn_s_setprio(0);

      // ---- P = exp2(s) (static max: |s| bounded << 126) + partial sum ----
      #pragma unroll
      for (int r = 0; r < 16; ++r) a[r] = exp2f(a[r]);
      float tr[8];
      #pragma unroll
      for (int r = 0; r < 8; ++r) tr[r] = a[r] + a[r + 8];
      #pragma unroll
      for (int s = 4; s > 0; s >>= 1)
        #pragma unroll
        for (int r = 0; r < s; ++r) tr[r] += tr[r + s];
      lrun += tr[0];

      // ---- PV for these 32 keys: O^T += V^T x P^T (P in-register) ----
      #pragma unroll
      for (int j = 0; j < 2; ++j) {
        const int base = j * 8;
        const unsigned a_h = pk_hi(a[base+0], a[base+1]);
        const unsigned b_h = pk_hi(a[base+4], a[base+5]);
        const unsigned c_h = pk_hi(a[base+2], a[base+3]);
        const unsigned d_h = pk_hi(a[base+6], a[base+7]);
        const unsigned a_l = pk_lo(a[base+0], a[base+1]);
        const unsigned b_l = pk_lo(a[base+4], a[base+5]);
        const unsigned c_l = pk_lo(a[base+2], a[base+3]);
        const unsigned d_l = pk_lo(a[base+6], a[base+7]);
        const u32x2 s1 = __builtin_amdgcn_permlane32_swap(a_h, b_h, false, false);
        const u32x2 s2 = __builtin_amdgcn_permlane32_swap(c_h, d_h, false, false);
        const u32x2 s3 = __builtin_amdgcn_permlane32_swap(a_l, b_l, false, false);
        const u32x2 s4 = __builtin_amdgcn_permlane32_swap(c_l, d_l, false, false);
        const u32x4 wH = {s1[0], s2[0], s1[1], s2[1]};
        const u32x4 wL = {s3[0], s4[0], s3[1], s4[1]};
        const s16x8 pH = __builtin_bit_cast(s16x8, wH);
        const s16x8 pL = __builtin_bit_cast(s16x8, wL);
        const size_t vb = vrow + (size_t)t * KVB + (cc * 2 + j) * 16 + hi * 8;
        const s16x8 vh = *(const s16x8*)&Vth[vb];
        const s16x8 vl = *(const s16x8*)&Vtl[vb];
        __builtin_amdgcn_s_setprio(1);
        o = mfma32(vh, pH, o);
        o = mfma32(vl, pH, o);
        o = mfma32(vh, pL, o);
        __builtin_amdgcn_s_setprio(0);
      }
    }
  }

  // ---- epilogue: l + unnormalized partial O via same-wave LDS transpose ----
  lrun += __shfl_xor(lrun, 32);    // merge the partner half's keys
  if (lane < 32) {
    const int g = (b * NH_ + h) * S_ + q0 + lq;
    Ml[(size_t)sp * ROWS_ + g] = lrun;
  }
  #pragma unroll
  for (int r = 0; r < 16; ++r) {
    const int d = (r & 3) + 8 * (r >> 2) + 4 * hi;
    ep[wv][lq][d] = o[r];
  }
  const int qq = lane >> 1, d0 = (lane & 1) * 16;   // same-wave region: no barrier
  const int g2 = (b * NH_ + h) * S_ + q0 + qq;
  float* dst = &Opart[((size_t)sp * ROWS_ + g2) * HD_ + d0];
  #pragma unroll
  for (int j = 0; j < 4; ++j)
    *(float4*)(dst + j * 4) = *(const float4*)&ep[wv][qq][d0 + j * 4];
}

// ---------------------------------------------------------------------------
// O projection with FUSED split-combine (NSPLIT=8 partials): per kt (=head),
// A-tile = (sum_s Opart_s) / (sum_s l_s), then bf16x3 GEMM against Wo.
// ---------------------------------------------------------------------------
__global__ __launch_bounds__(256)
void oproj(const float* __restrict__ Opart, const float* __restrict__ Ml,
           const float* __restrict__ Wo, const float* __restrict__ bo,
           float* __restrict__ out)
{
  union Sm {
    struct {
      short Ah[64][40], Al[64][40];
      short W0h[64][40], W0l[64][40];
    } s;
    float ep[64][76];
  };
  __shared__ __align__(16) Sm sm;

  const int tid = threadIdx.x;
  const int wv = tid >> 6, lane = tid & 63, lq = lane & 15, lg = lane >> 4;
  const int wm = wv >> 1, wn = wv & 1;
  int bid = blockIdx.x;                          // 128 blocks, nx=32
  bid = (bid & 7) * 16 + (bid >> 3);             // XCD swizzle
  const int m0 = (bid & 31) << 6, n0 = (bid >> 5) << 6;

  f32x4 acc0[2][2] = {};

  const int ar = tid >> 2, dc = (tid & 3) * 8;   // A-stage: row, d-col group
  const int ab = (m0 + ar) >> 9, aq = (m0 + ar) & (S_ - 1);
  float4 a0s, a1s;
  float lsum;
  float4 w0R[2];

  auto gload = [&](int kt) {
    const int g = (ab * NH_ + kt) * S_ + aq;     // head == kt (BK == HD)
    float ls = 0.f;
    float4 s0 = make_float4(0.f, 0.f, 0.f, 0.f);
    float4 s1 = make_float4(0.f, 0.f, 0.f, 0.f);
    #pragma unroll
    for (int s = 0; s < NSPLIT; ++s) {
      ls += Ml[(size_t)s * ROWS_ + g];
      const size_t base = ((size_t)s * ROWS_ + g) * HD_ + dc;
      const float4 o0 = *(const float4*)&Opart[base];
      const float4 o1 = *(const float4*)&Opart[base + 4];
      s0.x += o0.x; s0.y += o0.y; s0.z += o0.z; s0.w += o0.w;
      s1.x += o1.x; s1.y += o1.y; s1.z += o1.z; s1.w += o1.w;
    }
    lsum = ls; a0s = s0; a1s = s1;
    const int k0 = kt << 5;
    #pragma unroll
    for (int i = 0; i < 2; ++i) {
      const int idx = tid + (i << 8);
      const int n = idx >> 3, c4 = idx & 7;
      w0R[i] = *(const float4*)&Wo[(size_t)(n0 + n) * D_ + k0 + c4 * 4];
    }
  };
  auto stage = [&]() {
    const float inv = 1.0f / lsum;
    float4 a0 = make_float4(a0s.x * inv, a0s.y * inv, a0s.z * inv, a0s.w * inv);
    float4 a1 = make_float4(a1s.x * inv, a1s.y * inv, a1s.z * inv, a1s.w * inv);
    s16x4 hh, ll;
    split4(a0, hh, ll);
    *(s16x4*)&sm.s.Ah[ar][dc]     = hh;
    *(s16x4*)&sm.s.Al[ar][dc]     = ll;
    split4(a1, hh, ll);
    *(s16x4*)&sm.s.Ah[ar][dc + 4] = hh;
    *(s16x4*)&sm.s.Al[ar][dc + 4] = ll;
    #pragma unroll
    for (int i = 0; i < 2; ++i) {
      const int idx = tid + (i << 8);
      const int n = idx >> 3, c4 = idx & 7;
      s16x4 wh, wl; split4(w0R[i], wh, wl);
      *(s16x4*)&sm.s.W0h[n][c4 * 4] = wh;
      *(s16x4*)&sm.s.W0l[n][c4 * 4] = wl;
    }
  };

  gload(0);
  #pragma unroll
  for (int kt = 0; kt < 8; ++kt) {
    __syncthreads();
    stage();
    __syncthreads();
    if (kt < 7) gload(kt + 1);
    s16x8 ah[2], al[2];
    #pragma unroll
    for (int mi = 0; mi < 2; ++mi) {
      ah[mi] = *(const s16x8*)&sm.s.Ah[wm * 32 + mi * 16 + lq][lg * 8];
      al[mi] = *(const s16x8*)&sm.s.Al[wm * 32 + mi * 16 + lq][lg * 8];
    }
    #pragma unroll
    for (int ni = 0; ni < 2; ++ni) {
      const int nr = wn * 32 + ni * 16 + lq;
      const s16x8 bh = *(const s16x8*)&sm.s.W0h[nr][lg * 8];
      const s16x8 bl = *(const s16x8*)&sm.s.W0l[nr][lg * 8];
      #pragma unroll
      for (int mi = 0; mi < 2; ++mi) {
        acc0[mi][ni] = mfma_bf16(ah[mi], bh, acc0[mi][ni]);
        acc0[mi][ni] = mfma_bf16(al[mi], bh, acc0[mi][ni]);
        acc0[mi][ni] = mfma_bf16(ah[mi], bl, acc0[mi][ni]);
      }
    }
  }

  // ---- epilogue: fp32 out + bias ----
  __syncthreads();
  #pragma unroll
  for (int mi = 0; mi < 2; ++mi)
    #pragma unroll
    for (int ni = 0; ni < 2; ++ni)
      #pragma unroll
      for (int r = 0; r < 4; ++r)
        sm.ep[wm*32 + mi*16 + lg*4 + r][wn*32 + ni*16 + lq] = acc0[mi][ni][r];
  __syncthreads();
  #pragma unroll
  for (int i = 0; i < 4; ++i) {
    const int idx = tid + (i << 8);
    const int m = idx >> 4, c4 = idx & 15;
    const float4 v = *(const float4*)&sm.ep[m][c4 * 4];
    const float4 bb = *(const float4*)&bo[n0 + c4 * 4];
    *(float4*)&out[(size_t)(m0 + m) * D_ + n0 + c4 * 4] =
        make_float4(v.x + bb.x, v.y + bb.y, v.z + bb.z, v.w + bb.w);
  }
}

// ---------------------------------------------------------------------------
extern "C" void kernel_launch(void* const* d_in, const int* in_sizes, int n_in,
                              void* d_out, int out_size, void* d_ws, size_t ws_size,
                              hipStream_t stream)
{
  const float* query = (const float*)d_in[0];
  const float* keyva = (const float*)d_in[1];
  const float* Wq = (const float*)d_in[2];
  const float* bq = (const float*)d_in[3];
  const float* Wk = (const float*)d_in[4];
  const float* bk = (const float*)d_in[5];
  const float* Wv = (const float*)d_in[6];
  const float* bv = (const float*)d_in[7];
  const float* Wo = (const float*)d_in[8];
  const float* bo = (const float*)d_in[9];
  float* out = (float*)d_out;

  // workspace (~51.6 MiB high-water). Aliases (stream-ordered):
  //   Opart (16.78MB, exact) over KvtH+KvtL  (Kvt dead after gemm_kv)
  char* w = (char*)d_ws;
  short* KvtH = (short*)w; w += 8388608;
  short* KvtL = (short*)w; w += 8388608;
  short* Qh   = (short*)w; w += 1048576;
  short* Ql   = (short*)w; w += 1048576;
  short* Kh   = (short*)w; w += 8388608;
  short* Kl   = (short*)w; w += 8388608;
  short* VtH  = (short*)w; w += 8388608;
  short* VtL  = (short*)w; w += 8388608;
  short* WkH  = (short*)w; w += 262144;
  short* WkL  = (short*)w; w += 262144;
  short* WvH  = (short*)w; w += 262144;
  short* WvL  = (short*)w; w += 262144;
  float* Ml   = (float*)w; w += 524288;         // NSPLIT*ROWS_*4
  float* Opart= (float*)KvtH;                   // 8*16384*32*4 = 16777216 (exact)

  const dim3 blk(256);
  // 1/sqrt(32) * log2(e): attention computed in exp2 domain
  const float qscale = 0.17677669529663687f * 1.4426950408889634f;

  prep<<<dim3(1280), blk, 0, stream>>>(
      keyva, KvtH, KvtL, Wk, Wv, WkH, WkL, WvH, WvL,
      query, Wq, bq, Qh, Ql, qscale);

  gemm_kv<<<dim3(1024), blk, 0, stream>>>(
      KvtH, KvtL, WkH, WkL, bk, Kh, Kl, WvH, WvL, bv, VtH, VtL);

  attn_mfma32<<<dim3(NSPLIT * B_ * NH_ * (S_ / 128)), blk, 0, stream>>>(
      Qh, Ql, Kh, Kl, VtH, VtL, Opart, Ml);

  oproj<<<dim3(128), blk, 0, stream>>>(Opart, Ml, Wo, bo, out);
}